// Round 1
// baseline (258.112 us; speedup 1.0000x reference)
//
#include <hip/hip_runtime.h>
#include <stdint.h>

#define BATCH 128
#define VOCAB 128000
#define CPT 4            // columns per thread
#define TPB 256          // threads per block
#define COLBLOCKS 125    // VOCAB / (TPB*CPT) = 128000/1024

__device__ __forceinline__ uint32_t rotl32(uint32_t x, int r) {
  return (x << r) | (x >> (32 - r));
}

// JAX threefry2x32, key = (0, 42), returns x0 ^ x1 (partitionable 32-bit path)
__device__ __forceinline__ uint32_t tf_bits(uint32_t ctr_lo) {
  const uint32_t ks0 = 0u;
  const uint32_t ks1 = 42u;
  const uint32_t ks2 = 0x1BD11BF0u; // 0x1BD11BDA ^ 0 ^ 42
  uint32_t x0 = 0u + ks0;       // ctr_hi = 0 for sizes < 2^32
  uint32_t x1 = ctr_lo + ks1;

#define TF_R4(a, b, c, d)                              \
  x0 += x1; x1 = rotl32(x1, a); x1 ^= x0;              \
  x0 += x1; x1 = rotl32(x1, b); x1 ^= x0;              \
  x0 += x1; x1 = rotl32(x1, c); x1 ^= x0;              \
  x0 += x1; x1 = rotl32(x1, d); x1 ^= x0;

  TF_R4(13, 15, 26, 6)
  x0 += ks1; x1 += ks2 + 1u;
  TF_R4(17, 29, 16, 24)
  x0 += ks2; x1 += ks0 + 2u;
  TF_R4(13, 15, 26, 6)
  x0 += ks0; x1 += ks1 + 3u;
  TF_R4(17, 29, 16, 24)
  x0 += ks1; x1 += ks2 + 4u;
  TF_R4(13, 15, 26, 6)
  x0 += ks2; x1 += ks0 + 5u;
#undef TF_R4
  return x0 ^ x1;
}

// score = logit/T - log(noise), noise = -log(1-u), u = bits-derived uniform
__device__ __forceinline__ float score_from_bits(uint32_t bits, float s) {
  float f = __uint_as_float((bits >> 9) | 0x3F800000u); // [1,2)
  float q = 2.0f - f;        // == 1-u, exact in f32
  float noise = -__logf(q);  // Exp(1); q==1 -> -0.0f
  return s - __logf(noise);  // noise==0 -> -inf -> score=+inf (wins)
}

// float -> orderable uint (monotone)
__device__ __forceinline__ uint32_t order_f32(float sc) {
  uint32_t m = __float_as_uint(sc);
  return (m & 0x80000000u) ? ~m : (m | 0x80000000u);
}

__global__ __launch_bounds__(TPB) void init_ws(unsigned long long* best) {
  best[threadIdx.x] = 0ull; // smaller than any real packed value
}

__global__ __launch_bounds__(TPB) void sample_main(
    const float* __restrict__ logits, const float* __restrict__ temps,
    unsigned long long* __restrict__ best) {
  const int b   = blockIdx.x;          // 0 .. 128*125-1
  const int row = b / COLBLOCKS;
  const int cb  = b - row * COLBLOCKS;
  const int c0  = cb * (TPB * CPT) + threadIdx.x * CPT;

  const float invT = 1.0f / temps[row];
  const float4 lg = *reinterpret_cast<const float4*>(
      logits + (size_t)row * VOCAB + c0);
  const uint32_t i0 = (uint32_t)row * (uint32_t)VOCAB + (uint32_t)c0;

  float sv[4] = {lg.x, lg.y, lg.z, lg.w};
  unsigned long long bestv = 0ull;
#pragma unroll
  for (int k = 0; k < CPT; ++k) {
    uint32_t bits = tf_bits(i0 + (uint32_t)k);
    float sc = score_from_bits(bits, sv[k] * invT);
    // pack: high = orderable score, low = ~col (ties -> lowest index wins)
    unsigned long long p = ((unsigned long long)order_f32(sc) << 32) |
                           (uint32_t)(~(uint32_t)(c0 + k));
    bestv = (p > bestv) ? p : bestv;
  }

  // wave(64) max-reduce of packed value
#pragma unroll
  for (int off = 32; off > 0; off >>= 1) {
    unsigned long long o = __shfl_down(bestv, off, 64);
    bestv = (o > bestv) ? o : bestv;
  }
  if ((threadIdx.x & 63) == 0) {
    atomicMax(&best[row], bestv);
  }
}

__global__ __launch_bounds__(BATCH) void finalize(
    const unsigned long long* __restrict__ best, int* __restrict__ out) {
  const int i = threadIdx.x;
  out[i] = (int)(~(uint32_t)(best[i] & 0xFFFFFFFFull));
}

extern "C" void kernel_launch(void* const* d_in, const int* in_sizes, int n_in,
                              void* d_out, int out_size, void* d_ws, size_t ws_size,
                              hipStream_t stream) {
  const float* logits = (const float*)d_in[0];
  const float* temps  = (const float*)d_in[1];
  unsigned long long* best = (unsigned long long*)d_ws;
  int* out = (int*)d_out;

  hipLaunchKernelGGL(init_ws, dim3(1), dim3(BATCH), 0, stream, best);
  hipLaunchKernelGGL(sample_main, dim3(BATCH * COLBLOCKS), dim3(TPB), 0, stream,
                     logits, temps, best);
  hipLaunchKernelGGL(finalize, dim3(1), dim3(BATCH), 0, stream, best, out);
}

// Round 2
// 120.994 us; speedup vs baseline: 2.1333x; 2.1333x over previous
//
#include <hip/hip_runtime.h>
#include <stdint.h>

#define BATCH 128
#define VOCAB 128000
#define TPB 256
#define JCHUNKS 5                          // 5 float4 groups per thread
#define BLOCK_COLS (TPB * 4 * JCHUNKS)     // 5120 cols per block
#define BLOCKS_PER_ROW (VOCAB / BLOCK_COLS) // 25
#define GRID_A (BATCH * BLOCKS_PER_ROW)    // 3200

__device__ __forceinline__ uint32_t rotl32(uint32_t x, int r) {
  return (x << r) | (x >> (32 - r));
}

// JAX threefry2x32, key=(0,42), partitionable 32-bit path: out = x0^x1
__device__ __forceinline__ uint32_t tf_bits(uint32_t ctr_lo) {
  const uint32_t ks0 = 0u;
  const uint32_t ks1 = 42u;
  const uint32_t ks2 = 0x1BD11BF0u; // 0x1BD11BDA ^ 0 ^ 42
  uint32_t x0 = 0u + ks0;
  uint32_t x1 = ctr_lo + ks1;

#define TF_R4(a, b, c, d)                              \
  x0 += x1; x1 = rotl32(x1, a); x1 ^= x0;              \
  x0 += x1; x1 = rotl32(x1, b); x1 ^= x0;              \
  x0 += x1; x1 = rotl32(x1, c); x1 ^= x0;              \
  x0 += x1; x1 = rotl32(x1, d); x1 ^= x0;

  TF_R4(13, 15, 26, 6)
  x0 += ks1; x1 += ks2 + 1u;
  TF_R4(17, 29, 16, 24)
  x0 += ks2; x1 += ks0 + 2u;
  TF_R4(13, 15, 26, 6)
  x0 += ks0; x1 += ks1 + 3u;
  TF_R4(17, 29, 16, 24)
  x0 += ks1; x1 += ks2 + 4u;
  TF_R4(13, 15, 26, 6)
  x0 += ks2; x1 += ks0 + 5u;
#undef TF_R4
  return x0 ^ x1;
}

// score = s - log(noise), noise = -log(1-u); identical math to round-1 (absmax 0)
__device__ __forceinline__ float score_from_bits(uint32_t bits, float s) {
  float f = __uint_as_float((bits >> 9) | 0x3F800000u); // [1,2)
  float q = 2.0f - f;        // == 1-u, exact
  float noise = -__logf(q);  // Exp(1)
  return s - __logf(noise);  // noise==0 -> +inf wins
}

// monotone float -> orderable u32 (branchless)
__device__ __forceinline__ uint32_t order_f32(float sc) {
  uint32_t m = __float_as_uint(sc);
  return m ^ (uint32_t)(((int32_t)m >> 31) | 0x80000000);
}

__global__ __launch_bounds__(TPB) void sample_main(
    const float* __restrict__ logits, const float* __restrict__ temps,
    unsigned long long* __restrict__ part) {
  const int b   = blockIdx.x;
  const int row = b / BLOCKS_PER_ROW;
  const int cb  = b - row * BLOCKS_PER_ROW;
  const int colBase = cb * BLOCK_COLS;           // block's first column

  const float invT = 1.0f / temps[row];
  const float* rowp = logits + (size_t)row * VOCAB;
  const uint32_t rowOff = (uint32_t)row * (uint32_t)VOCAB;

  // load 5 coalesced float4 groups (stride 1024 floats)
  float4 lg[JCHUNKS];
  int col4[JCHUNKS];
#pragma unroll
  for (int j = 0; j < JCHUNKS; ++j) {
    col4[j] = colBase + j * (TPB * 4) + threadIdx.x * 4;
    lg[j] = *reinterpret_cast<const float4*>(rowp + col4[j]);
  }

  uint32_t bestU = 0u;
  uint32_t bestCol = 0u;
#pragma unroll
  for (int j = 0; j < JCHUNKS; ++j) {
    float sv[4] = {lg[j].x, lg[j].y, lg[j].z, lg[j].w};
#pragma unroll
    for (int k = 0; k < 4; ++k) {
      const uint32_t col = (uint32_t)(col4[j] + k);
      uint32_t bits = tf_bits(rowOff + col);
      uint32_t u = order_f32(score_from_bits(bits, sv[k] * invT));
      // strict '>' keeps earliest col within thread (cols ascend per j,k? not
      // strictly across j — handle tie explicitly)
      if (u > bestU || (u == bestU && col < bestCol)) { bestU = u; bestCol = col; }
    }
  }

  // wave(64) reduce on (bestU, bestCol), lowest col wins ties
#pragma unroll
  for (int off = 32; off > 0; off >>= 1) {
    uint32_t oU = __shfl_down(bestU, off, 64);
    uint32_t oC = __shfl_down(bestCol, off, 64);
    if (oU > bestU || (oU == bestU && oC < bestCol)) { bestU = oU; bestCol = oC; }
  }

  __shared__ unsigned long long sm[TPB / 64];
  const int wid = threadIdx.x >> 6;
  if ((threadIdx.x & 63) == 0) {
    sm[wid] = ((unsigned long long)bestU << 32) | (uint32_t)(~bestCol);
  }
  __syncthreads();
  if (threadIdx.x == 0) {
    unsigned long long bv = sm[0];
#pragma unroll
    for (int w = 1; w < TPB / 64; ++w) bv = (sm[w] > bv) ? sm[w] : bv;
    part[b] = bv;   // plain store — no atomics
  }
}

__global__ __launch_bounds__(64) void reduce_rows(
    const unsigned long long* __restrict__ part, int* __restrict__ out) {
  const int r = blockIdx.x;
  const int t = threadIdx.x;
  unsigned long long bv = (t < BLOCKS_PER_ROW) ? part[r * BLOCKS_PER_ROW + t] : 0ull;
#pragma unroll
  for (int off = 32; off > 0; off >>= 1) {
    unsigned long long o = __shfl_down(bv, off, 64);
    bv = (o > bv) ? o : bv;
  }
  if (t == 0) out[r] = (int)(~(uint32_t)(bv & 0xFFFFFFFFull));
}

extern "C" void kernel_launch(void* const* d_in, const int* in_sizes, int n_in,
                              void* d_out, int out_size, void* d_ws, size_t ws_size,
                              hipStream_t stream) {
  const float* logits = (const float*)d_in[0];
  const float* temps  = (const float*)d_in[1];
  unsigned long long* part = (unsigned long long*)d_ws; // 3200 * 8B = 25.6 KB
  int* out = (int*)d_out;

  hipLaunchKernelGGL(sample_main, dim3(GRID_A), dim3(TPB), 0, stream,
                     logits, temps, part);
  hipLaunchKernelGGL(reduce_rows, dim3(BATCH), dim3(64), 0, stream, part, out);
}

// Round 3
// 114.463 us; speedup vs baseline: 2.2550x; 1.0571x over previous
//
#include <hip/hip_runtime.h>
#include <stdint.h>

#define BATCH 128
#define VOCAB 128000
#define TPB 256
#define JCH 5                                // float4 groups per thread
#define BLOCK_COLS (TPB * 4 * JCH)           // 5120
#define BPR (VOCAB / BLOCK_COLS)             // 25 blocks per row
#define GRID_A (BATCH * BPR)                 // 3200

__device__ __forceinline__ uint32_t rotl(uint32_t x, int r) {
#if __has_builtin(__builtin_rotateleft32)
  return __builtin_rotateleft32(x, (uint32_t)r);
#else
  return (x << r) | (x >> (32 - r));
#endif
}

// JAX threefry2x32, key=(0,42), partitionable: out = x0^x1 for ctr=(0, i).
// x1in = i + 42 (key-add prefolded); x0 starts at 0 so round-1 add is a copy.
__device__ __forceinline__ uint32_t tf_from_init(uint32_t x1) {
  uint32_t x0 = x1;                       // x0 = 0 + x1
  x1 = rotl(x1, 13) ^ x0;
  x0 += x1; x1 = rotl(x1, 15) ^ x0;
  x0 += x1; x1 = rotl(x1, 26) ^ x0;
  x0 += x1; x1 = rotl(x1,  6) ^ x0;
  x0 += 42u;          x1 += 0x1BD11BF1u;  // ks1, ks2+1
  x0 += x1; x1 = rotl(x1, 17) ^ x0;
  x0 += x1; x1 = rotl(x1, 29) ^ x0;
  x0 += x1; x1 = rotl(x1, 16) ^ x0;
  x0 += x1; x1 = rotl(x1, 24) ^ x0;
  x0 += 0x1BD11BF0u;  x1 += 2u;           // ks2, ks0+2
  x0 += x1; x1 = rotl(x1, 13) ^ x0;
  x0 += x1; x1 = rotl(x1, 15) ^ x0;
  x0 += x1; x1 = rotl(x1, 26) ^ x0;
  x0 += x1; x1 = rotl(x1,  6) ^ x0;
  /* x0 += ks0 (0) */ x1 += 45u;          // ks0, ks1+3
  x0 += x1; x1 = rotl(x1, 17) ^ x0;
  x0 += x1; x1 = rotl(x1, 29) ^ x0;
  x0 += x1; x1 = rotl(x1, 16) ^ x0;
  x0 += x1; x1 = rotl(x1, 24) ^ x0;
  x0 += 42u;          x1 += 0x1BD11BF4u;  // ks1, ks2+4
  x0 += x1; x1 = rotl(x1, 13) ^ x0;
  x0 += x1; x1 = rotl(x1, 15) ^ x0;
  x0 += x1; x1 = rotl(x1, 26) ^ x0;
  x0 += x1; x1 = rotl(x1,  6) ^ x0;
  x0 += 0x1BD11BF0u;  x1 += 5u;           // ks2, ks0+5
  return x0 ^ x1;
}

// score = s*invT - ln(noise), noise = -ln(1-u) = -ln2*log2(q), q = 2-f.
// Folded: score = sp - ln2*log2(-log2(q)), sp = s*invT + 0.36651292 (= -ln(ln2)).
__device__ __forceinline__ float score_from_bits(uint32_t bits, float sp) {
  uint32_t fb = (bits >> 9) | 0x3F800000u;      // f in [1,2)
  float q = 2.0f - __uint_as_float(fb);         // = 1-u, exact
  float t = __log2f(q);                         // <= 0; q==1 -> -0
  float l = __log2f(0.0f - t);                  // -t>=0; -0 -> log2(0) = -inf
  return __builtin_fmaf(l, -0.69314718f, sp);   // -inf -> score = +inf (wins)
}

__device__ __forceinline__ uint32_t order_f32(float sc) {
  uint32_t m = __float_as_uint(sc);
  return m ^ (uint32_t)(((int32_t)m >> 31) | 0x80000000);
}

__global__ __launch_bounds__(TPB) void sample_main(
    const float* __restrict__ logits, const float* __restrict__ temps,
    unsigned long long* __restrict__ part) {
  const int b   = blockIdx.x;
  const int row = b / BPR;
  const int cb  = b - row * BPR;
  const int colBase = cb * BLOCK_COLS;
  const int tcol = colBase + (int)threadIdx.x * 4;   // this thread's first col

  const float invT = 1.0f / temps[row];
  const float* rowp = logits + (size_t)row * VOCAB;

  float4 lg[JCH];
#pragma unroll
  for (int j = 0; j < JCH; ++j)
    lg[j] = *reinterpret_cast<const float4*>(rowp + tcol + j * (TPB * 4));

  // x1 init base: rowOff + tcol + 42; per-element offset j*1024+k is a literal
  const uint32_t c42 = (uint32_t)row * (uint32_t)VOCAB + (uint32_t)tcol + 42u;

  float bestS = -__builtin_inff();
  uint32_t bestJK = 0u;
#pragma unroll
  for (int j = 0; j < JCH; ++j) {
    float sv[4] = {lg[j].x, lg[j].y, lg[j].z, lg[j].w};
#pragma unroll
    for (int k = 0; k < 4; ++k) {
      const uint32_t jk = (uint32_t)(j * 4 + k);
      uint32_t bits = tf_from_init(c42 + (uint32_t)(j * 1024 + k));
      float sp = __builtin_fmaf(sv[k], invT, 0.36651292f);
      float sc = score_from_bits(bits, sp);
      bestJK = (sc > bestS) ? jk : bestJK;     // strict >: earliest col on tie
      bestS  = fmaxf(bestS, sc);
    }
  }

  // reconstruct this thread's winning column, pack (orderable score, ~col)
  const uint32_t col = (uint32_t)tcol + ((bestJK >> 2) << 10) + (bestJK & 3u);
  unsigned long long p =
      ((unsigned long long)order_f32(bestS) << 32) | (uint32_t)(~col);

  // wave(64) max-reduce of packed value (ties -> lowest col via ~col)
#pragma unroll
  for (int off = 32; off > 0; off >>= 1) {
    unsigned long long o = __shfl_down(p, off, 64);
    p = (o > p) ? o : p;
  }

  __shared__ unsigned long long sm[TPB / 64];
  if ((threadIdx.x & 63) == 0) sm[threadIdx.x >> 6] = p;
  __syncthreads();
  if (threadIdx.x == 0) {
    unsigned long long bv = sm[0];
#pragma unroll
    for (int w = 1; w < TPB / 64; ++w) bv = (sm[w] > bv) ? sm[w] : bv;
    part[b] = bv;
  }
}

__global__ __launch_bounds__(64) void reduce_rows(
    const unsigned long long* __restrict__ part, int* __restrict__ out) {
  const int r = blockIdx.x;
  const int t = threadIdx.x;
  unsigned long long bv = (t < BPR) ? part[r * BPR + t] : 0ull;
#pragma unroll
  for (int off = 32; off > 0; off >>= 1) {
    unsigned long long o = __shfl_down(bv, off, 64);
    bv = (o > bv) ? o : bv;
  }
  if (t == 0) out[r] = (int)(~(uint32_t)(bv & 0xFFFFFFFFull));
}

extern "C" void kernel_launch(void* const* d_in, const int* in_sizes, int n_in,
                              void* d_out, int out_size, void* d_ws, size_t ws_size,
                              hipStream_t stream) {
  const float* logits = (const float*)d_in[0];
  const float* temps  = (const float*)d_in[1];
  unsigned long long* part = (unsigned long long*)d_ws;  // 3200*8B = 25.6 KB
  int* out = (int*)d_out;

  hipLaunchKernelGGL(sample_main, dim3(GRID_A), dim3(TPB), 0, stream,
                     logits, temps, part);
  hipLaunchKernelGGL(reduce_rows, dim3(BATCH), dim3(64), 0, stream, part, out);
}

// Round 4
// 114.202 us; speedup vs baseline: 2.2601x; 1.0023x over previous
//
#include <hip/hip_runtime.h>
#include <stdint.h>

#define BATCH 128
#define VOCAB 128000
#define TPB 256
#define JCH 5                                // float4 groups per thread
#define BLOCK_COLS (TPB * 4 * JCH)           // 5120
#define BPR (VOCAB / BLOCK_COLS)             // 25 blocks per row
#define GRID_A (BATCH * BPR)                 // 3200

__device__ __forceinline__ uint32_t rotl(uint32_t x, int r) {
#if __has_builtin(__builtin_rotateleft32)
  return __builtin_rotateleft32(x, (uint32_t)r);
#else
  return (x << r) | (x >> (32 - r));
#endif
}

// JAX threefry2x32, key=(0,42), partitionable: out = x0^x1 for ctr=(0,i).
// Input: x1 = i + 42 (key-add prefolded). x0 starts 0 so round-1 add = copy.
__device__ __forceinline__ uint32_t tf_from_init(uint32_t x1) {
  uint32_t x0 = x1;
  x1 = rotl(x1, 13) ^ x0;
  x0 += x1; x1 = rotl(x1, 15) ^ x0;
  x0 += x1; x1 = rotl(x1, 26) ^ x0;
  x0 += x1; x1 = rotl(x1,  6) ^ x0;
  x0 += 42u;          x1 += 0x1BD11BF1u;  // ks1, ks2+1
  x0 += x1; x1 = rotl(x1, 17) ^ x0;
  x0 += x1; x1 = rotl(x1, 29) ^ x0;
  x0 += x1; x1 = rotl(x1, 16) ^ x0;
  x0 += x1; x1 = rotl(x1, 24) ^ x0;
  x0 += 0x1BD11BF0u;  x1 += 2u;           // ks2, ks0+2
  x0 += x1; x1 = rotl(x1, 13) ^ x0;
  x0 += x1; x1 = rotl(x1, 15) ^ x0;
  x0 += x1; x1 = rotl(x1, 26) ^ x0;
  x0 += x1; x1 = rotl(x1,  6) ^ x0;
  /* ks0 = 0 */       x1 += 45u;          // ks1+3
  x0 += x1; x1 = rotl(x1, 17) ^ x0;
  x0 += x1; x1 = rotl(x1, 29) ^ x0;
  x0 += x1; x1 = rotl(x1, 16) ^ x0;
  x0 += x1; x1 = rotl(x1, 24) ^ x0;
  x0 += 42u;          x1 += 0x1BD11BF4u;  // ks1, ks2+4
  x0 += x1; x1 = rotl(x1, 13) ^ x0;
  x0 += x1; x1 = rotl(x1, 15) ^ x0;
  x0 += x1; x1 = rotl(x1, 26) ^ x0;
  x0 += x1; x1 = rotl(x1,  6) ^ x0;
  x0 += 0x1BD11BF0u;  x1 += 5u;           // ks2, ks0+5
  return x0 ^ x1;
}

// score = sp - ln2*log2(-log2(2-f)), sp = s*invT - ln(ln2). Bit-exact vs ref
// (verified absmax 0 in rounds 1-3). Zero-mantissa draw -> +inf (wins).
__device__ __forceinline__ float score_one(uint32_t bits, float sp) {
  uint32_t fb = (bits >> 9) | 0x3F800000u;
  float q = 2.0f - __uint_as_float(fb);
  float t = __log2f(q);
  float l = __log2f(-t);                       // neg = free input modifier
  return __builtin_fmaf(l, -0.69314718f, sp);
}

__device__ __forceinline__ uint32_t order_f32(float sc) {
  uint32_t m = __float_as_uint(sc);
  return m ^ (uint32_t)(((int32_t)m >> 31) | 0x80000000);
}

// One element, all-literal ctr offset + slot id. No arrays anywhere.
#define ELEM(av, CTR, JK)                                          \
  {                                                                \
    uint32_t bits = tf_from_init(c42 + (uint32_t)(CTR));           \
    float sp = __builtin_fmaf((av), invT, 0.36651292f);            \
    float sc = score_one(bits, sp);                                \
    bestJK = (sc > bestS) ? (uint32_t)(JK) : bestJK;               \
    bestS = fmaxf(bestS, sc);                                      \
  }

__global__ __launch_bounds__(TPB) void sample_main(
    const float* __restrict__ logits, const float* __restrict__ temps,
    unsigned long long* __restrict__ part) {
  const int b   = blockIdx.x;
  const int row = b / BPR;
  const int cb  = b - row * BPR;
  const int tcol = cb * BLOCK_COLS + (int)threadIdx.x * 4;

  const float invT = 1.0f / temps[row];
  const float* p0 = logits + (size_t)row * VOCAB + tcol;

  // 5 coalesced float4 loads, named scalars only (no indexed arrays)
  const float4 a0 = *reinterpret_cast<const float4*>(p0);
  const float4 a1 = *reinterpret_cast<const float4*>(p0 + 1024);
  const float4 a2 = *reinterpret_cast<const float4*>(p0 + 2048);
  const float4 a3 = *reinterpret_cast<const float4*>(p0 + 3072);
  const float4 a4 = *reinterpret_cast<const float4*>(p0 + 4096);

  const uint32_t c42 = (uint32_t)row * (uint32_t)VOCAB + (uint32_t)tcol + 42u;

  float bestS = -__builtin_inff();
  uint32_t bestJK = 0u;

  ELEM(a0.x,    0,  0) ELEM(a0.y,    1,  1) ELEM(a0.z,    2,  2) ELEM(a0.w,    3,  3)
  ELEM(a1.x, 1024,  4) ELEM(a1.y, 1025,  5) ELEM(a1.z, 1026,  6) ELEM(a1.w, 1027,  7)
  ELEM(a2.x, 2048,  8) ELEM(a2.y, 2049,  9) ELEM(a2.z, 2050, 10) ELEM(a2.w, 2051, 11)
  ELEM(a3.x, 3072, 12) ELEM(a3.y, 3073, 13) ELEM(a3.z, 3074, 14) ELEM(a3.w, 3075, 15)
  ELEM(a4.x, 4096, 16) ELEM(a4.y, 4097, 17) ELEM(a4.z, 4098, 18) ELEM(a4.w, 4099, 19)

  // reconstruct winning column; pack (orderable score, ~col)
  const uint32_t col = (uint32_t)tcol + ((bestJK >> 2) << 10) + (bestJK & 3u);
  unsigned long long p =
      ((unsigned long long)order_f32(bestS) << 32) | (uint32_t)(~col);

#pragma unroll
  for (int off = 32; off > 0; off >>= 1) {
    unsigned long long o = __shfl_down(p, off, 64);
    p = (o > p) ? o : p;
  }

  __shared__ unsigned long long sm[TPB / 64];
  if ((threadIdx.x & 63) == 0) sm[threadIdx.x >> 6] = p;
  __syncthreads();
  if (threadIdx.x == 0) {
    unsigned long long bv = sm[0];
    bv = (sm[1] > bv) ? sm[1] : bv;
    bv = (sm[2] > bv) ? sm[2] : bv;
    bv = (sm[3] > bv) ? sm[3] : bv;
    part[b] = bv;
  }
}

__global__ __launch_bounds__(64) void reduce_rows(
    const unsigned long long* __restrict__ part, int* __restrict__ out) {
  const int r = blockIdx.x;
  const int t = threadIdx.x;
  unsigned long long bv = (t < BPR) ? part[r * BPR + t] : 0ull;
#pragma unroll
  for (int off = 32; off > 0; off >>= 1) {
    unsigned long long o = __shfl_down(bv, off, 64);
    bv = (o > bv) ? o : bv;
  }
  if (t == 0) out[r] = (int)(~(uint32_t)(bv & 0xFFFFFFFFull));
}

extern "C" void kernel_launch(void* const* d_in, const int* in_sizes, int n_in,
                              void* d_out, int out_size, void* d_ws, size_t ws_size,
                              hipStream_t stream) {
  const float* logits = (const float*)d_in[0];
  const float* temps  = (const float*)d_in[1];
  unsigned long long* part = (unsigned long long*)d_ws;  // 3200*8B = 25.6 KB
  int* out = (int*)d_out;

  hipLaunchKernelGGL(sample_main, dim3(GRID_A), dim3(TPB), 0, stream,
                     logits, temps, part);
  hipLaunchKernelGGL(reduce_rows, dim3(BATCH), dim3(64), 0, stream, part, out);
}